// Round 1
// baseline (10322.597 us; speedup 1.0000x reference)
//
#include <hip/hip_runtime.h>

#define EPS 1e-5f

typedef __attribute__((ext_vector_type(8))) short s8v;   // 8 x bf16 bits (4 VGPRs)
typedef __attribute__((ext_vector_type(4))) float f4v;   // MFMA accumulator

__device__ __forceinline__ unsigned short f2b(float x) {
  unsigned int u = __float_as_uint(x);
  u += 0x7FFFu + ((u >> 16) & 1u);          // round-to-nearest-even
  return (unsigned short)(u >> 16);
}
__device__ __forceinline__ float b2f(unsigned short b) {
  return __uint_as_float(((unsigned int)b) << 16);
}

enum { EPI_PLAIN = 0, EPI_BN = 1, EPI_D3 = 2, EPI_BN3 = 3 };

// C(MxN) = epilogue(A(MxK) * B(NxK)^T). M % 64 == 0 always in this net.
// 64x64 tile, BK=32, 4 waves each 32x32 (2x2 frags of 16x16x32 bf16 MFMA).
// A/B staged f32->bf16 into LDS (row stride 40 bf16 = 80B, 16B-aligned, padded).
template<int EPI, bool RES, bool ABF16>
__global__ __launch_bounds__(256)
void gemm_k(const void* Aptr, int lda,
            const float* __restrict__ Bw, int ldb,
            const float* __restrict__ bias,
            const float* __restrict__ q0, const float* __restrict__ q1,
            const float* __restrict__ q2, const float* __restrict__ q3,
            const float* __restrict__ aux0, const float* __restrict__ aux1,
            void* Cptr, float* __restrict__ Dout,
            int M, int N, int K)
{
  __shared__ unsigned short As[64 * 40];
  __shared__ unsigned short Bs[64 * 40];
  const int t  = threadIdx.x;
  const int MT = M >> 6;
  const int mt = (int)blockIdx.x % MT;
  const int nt = (int)blockIdx.x / MT;
  const int m0 = mt << 6, n0 = nt << 6;

  const int lane = t & 63, w = t >> 6;
  const int wm = (w >> 1) << 5, wn = (w & 1) << 5;
  const int lr = lane & 15, lk = lane >> 4;

  const int sr = t >> 5;   // staging row base 0..7
  const int sk = t & 31;   // staging k 0..31 (coalesced across lanes)

  f4v acc[2][2] = {{{0.f,0.f,0.f,0.f},{0.f,0.f,0.f,0.f}},
                   {{0.f,0.f,0.f,0.f},{0.f,0.f,0.f,0.f}}};

  for (int k0 = 0; k0 < K; k0 += 32) {
    const int kg = k0 + sk;
    const bool kin = (kg < K);
    #pragma unroll
    for (int it = 0; it < 8; ++it) {
      const int row = sr + (it << 3);
      float av = 0.f;
      if (kin) {
        if (ABF16) av = b2f(((const unsigned short*)Aptr)[(size_t)(m0 + row) * lda + kg]);
        else       av = ((const float*)Aptr)[(size_t)(m0 + row) * lda + kg];
      }
      As[row * 40 + sk] = f2b(av);
      const int brow = n0 + row;
      float bv = 0.f;
      if (kin && brow < N) bv = Bw[(size_t)brow * ldb + kg];
      Bs[row * 40 + sk] = f2b(bv);
    }
    __syncthreads();
    s8v a0 = *(const s8v*)(As + (wm + lr) * 40 + lk * 8);
    s8v a1 = *(const s8v*)(As + (wm + 16 + lr) * 40 + lk * 8);
    s8v b0 = *(const s8v*)(Bs + (wn + lr) * 40 + lk * 8);
    s8v b1 = *(const s8v*)(Bs + (wn + 16 + lr) * 40 + lk * 8);
    acc[0][0] = __builtin_amdgcn_mfma_f32_16x16x32_bf16(a0, b0, acc[0][0], 0, 0, 0);
    acc[0][1] = __builtin_amdgcn_mfma_f32_16x16x32_bf16(a0, b1, acc[0][1], 0, 0, 0);
    acc[1][0] = __builtin_amdgcn_mfma_f32_16x16x32_bf16(a1, b0, acc[1][0], 0, 0, 0);
    acc[1][1] = __builtin_amdgcn_mfma_f32_16x16x32_bf16(a1, b1, acc[1][1], 0, 0, 0);
    __syncthreads();
  }

  // C/D frag layout (m89-verified): col = lane&15, row = (lane>>4)*4 + reg
  #pragma unroll
  for (int fm = 0; fm < 2; ++fm) {
    #pragma unroll
    for (int fn = 0; fn < 2; ++fn) {
      #pragma unroll
      for (int j = 0; j < 4; ++j) {
        const int row = m0 + wm + fm * 16 + lk * 4 + j;
        const int col = n0 + wn + fn * 16 + lr;
        if (col >= N) continue;
        float v = acc[fm][fn][j];
        const size_t idx = (size_t)row * (size_t)N + col;
        if (EPI == EPI_PLAIN) {
          v += bias[col];
          v = fmaxf(v, 0.f);
          ((float*)Cptr)[idx] = v;
        } else if (EPI == EPI_BN) {
          v += bias[col];
          const float s = q0[col] * rsqrtf(q3[col] + EPS);
          v = (v - q2[col]) * s + q1[col];
          v = fmaxf(v, 0.f);
          if (RES) v += aux0[idx];
          ((float*)Cptr)[idx] = v;
          if (Dout) Dout[idx] = v;
        } else if (EPI == EPI_D3) {
          // d3 = acc(env part) + blin + h[b,i] * Wlin[i,o,53]; no relu, out bf16
          const int i = col / 54;
          v += bias[col];
          v = fmaf(aux0[(size_t)row * 2666 + i], aux1[(size_t)col * 54 + 53], v);
          ((unsigned short*)Cptr)[idx] = f2b(v);
        } else { // EPI_BN3: per-row-i batchnorm, relu, out bf16
          const int i = row % 2666;
          v += bias[col];
          const float s = q0[i] * rsqrtf(q3[i] + EPS);
          v = (v - q2[i]) * s + q1[i];
          v = fmaxf(v, 0.f);
          ((unsigned short*)Cptr)[idx] = f2b(v);
        }
      }
    }
  }
}

// W15 stage: h5[rr*5+p] = relu(bn3_2( h3b[rr,:] . W15[p,:] + b15[p] )), rr = b*2666+i
__global__ __launch_bounds__(256)
void w15_k(const unsigned short* __restrict__ H, const float* __restrict__ W15,
           const float* __restrict__ b15,
           const float* __restrict__ g, const float* __restrict__ bb,
           const float* __restrict__ rm, const float* __restrict__ rv,
           float* __restrict__ out)
{
  __shared__ float wsh[5 * 54 + 5];
  const int t = threadIdx.x;
  for (int idx = t; idx < 270; idx += 256) wsh[idx] = W15[idx];
  if (t < 5) wsh[270 + t] = b15[t];
  __syncthreads();
  const size_t rr = (size_t)blockIdx.x * 256 + t;   // grid 2666 * 256 == 682496 exactly
  float hv[54];
  #pragma unroll
  for (int c = 0; c < 54; ++c) hv[c] = b2f(H[rr * 54 + c]);
  const int i = (int)(rr % 2666);
  const float s = g[i] * rsqrtf(rv[i] + EPS);
  #pragma unroll
  for (int p = 0; p < 5; ++p) {
    float a = wsh[270 + p];
    #pragma unroll
    for (int c = 0; c < 54; ++c) a = fmaf(hv[c], wsh[p * 54 + c], a);
    a = (a - rm[i]) * s + bb[i];
    out[rr * 5 + p] = fmaxf(a, 0.f);
  }
}

extern "C" void kernel_launch(void* const* d_in, const int* in_sizes, int n_in,
                              void* d_out, int out_size, void* d_ws, size_t ws_size,
                              hipStream_t stream)
{
  const float* x    = (const float*)d_in[0];
  const float* W1   = (const float*)d_in[1];
  const float* b1   = (const float*)d_in[2];
  const float* Wmid = (const float*)d_in[3];
  const float* bmid = (const float*)d_in[4];
  const float* bng  = (const float*)d_in[5];
  const float* bnb  = (const float*)d_in[6];
  const float* bnrm = (const float*)d_in[7];
  const float* bnrv = (const float*)d_in[8];
  const float* Wlin = (const float*)d_in[9];
  const float* blin = (const float*)d_in[10];
  const float* W13  = (const float*)d_in[11];
  const float* b13  = (const float*)d_in[12];
  const float* W14  = (const float*)d_in[13];
  const float* b14  = (const float*)d_in[14];
  const float* W15  = (const float*)d_in[15];
  const float* b15  = (const float*)d_in[16];
  const float* bn3g = (const float*)d_in[17];
  const float* bn3b = (const float*)d_in[18];
  const float* bn3rm= (const float*)d_in[19];
  const float* bn3rv= (const float*)d_in[20];
  const float* W16  = (const float*)d_in[21];
  const float* b16  = (const float*)d_in[22];
  const float* W17  = (const float*)d_in[23];
  const float* b17  = (const float*)d_in[24];
  const float* W18  = (const float*)d_in[25];
  const float* b18  = (const float*)d_in[26];

  const int R = 2666;
  char* ws = (char*)d_ws;
  float* hA = (float*)ws;                       ws += (size_t)256 * R * 4;
  float* hB = (float*)ws;                       ws += (size_t)256 * R * 4;
  float* dR = (float*)ws;                       ws += (size_t)256 * R * 4;
  unsigned short* big0 = (unsigned short*)ws;   ws += (size_t)256 * 143964 * 2; // d3 / h3a / h3b (in-place)
  float* h5 = (float*)ws;                       ws += (size_t)256 * 13330 * 4;
  float* h6 = (float*)ws;                       ws += (size_t)256 * 750 * 4;
  float* h7 = (float*)ws;                       /* total ~97 MB */

  dim3 TB(256);
  #define NB(M, N) dim3((unsigned)(((M) >> 6) * (((N) + 63) >> 6)))

  // L1: h = relu(bn0(x_geno @ W1^T + b1)); d = h
  gemm_k<EPI_BN, false, false><<<NB(256, R), TB, 0, stream>>>(
      x, 16437, W1, 16384, b1, bng, bnb, bnrm, bnrv,
      nullptr, nullptr, hA, dR, 256, R, 16384);

  // 10 mid layers with residual after each pair
  const float* cur = hA; float* nxt = hB;
  for (int k = 0; k < 10; ++k) {
    const float* bw = Wmid + (size_t)k * R * R;
    const float* bs = bmid + (size_t)k * R;
    const int L = k + 1;
    if ((k & 1) == 0) {
      gemm_k<EPI_BN, false, false><<<NB(256, R), TB, 0, stream>>>(
          cur, R, bw, R, bs, bng + (size_t)L * R, bnb + (size_t)L * R,
          bnrm + (size_t)L * R, bnrv + (size_t)L * R,
          nullptr, nullptr, nxt, nullptr, 256, R, R);
    } else {
      gemm_k<EPI_BN, true, false><<<NB(256, R), TB, 0, stream>>>(
          cur, R, bw, R, bs, bng + (size_t)L * R, bnb + (size_t)L * R,
          bnrm + (size_t)L * R, bnrv + (size_t)L * R,
          dR, nullptr, nxt, dR, 256, R, R);
    }
    float* tmp = (float*)cur; cur = nxt; nxt = tmp;
  }
  // k = 10 (bn layer 11, no residual)
  gemm_k<EPI_BN, false, false><<<NB(256, R), TB, 0, stream>>>(
      cur, R, Wmid + (size_t)10 * R * R, R, bmid + (size_t)10 * R,
      bng + (size_t)11 * R, bnb + (size_t)11 * R, bnrm + (size_t)11 * R, bnrv + (size_t)11 * R,
      nullptr, nullptr, nxt, nullptr, 256, R, R);
  const float* hfin = nxt;

  // d3 as GEMM: env(256x53) @ Wlin[:,:,0:53]^T (143964x53); h-term + blin in epilogue
  gemm_k<EPI_D3, false, false><<<NB(256, 143964), TB, 0, stream>>>(
      x + 16384, 16437, Wlin, 54, blin, nullptr, nullptr, nullptr, nullptr,
      hfin, Wlin, big0, nullptr, 256, 143964, 53);

  // W13: (682496x54) @ (54x54)^T, bn3 j=0, in-place bf16
  gemm_k<EPI_BN3, false, true><<<NB(682496, 54), TB, 0, stream>>>(
      big0, 54, W13, 54, b13, bn3g, bn3b, bn3rm, bn3rv,
      nullptr, nullptr, big0, nullptr, 682496, 54, 54);
  // W14: bn3 j=1, in-place
  gemm_k<EPI_BN3, false, true><<<NB(682496, 54), TB, 0, stream>>>(
      big0, 54, W14, 54, b14, bn3g + R, bn3b + R, bn3rm + R, bn3rv + R,
      nullptr, nullptr, big0, nullptr, 682496, 54, 54);
  // W15: -> h5 (256 x 13330) f32
  w15_k<<<dim3(2666), TB, 0, stream>>>(big0, W15, b15,
      bn3g + 2 * R, bn3b + 2 * R, bn3rm + 2 * R, bn3rv + 2 * R, h5);

  // Tail MLP
  gemm_k<EPI_PLAIN, false, false><<<NB(256, 750), TB, 0, stream>>>(
      h5, 13330, W16, 13330, b16, nullptr, nullptr, nullptr, nullptr,
      nullptr, nullptr, h6, nullptr, 256, 750, 13330);
  gemm_k<EPI_PLAIN, false, false><<<NB(256, 750), TB, 0, stream>>>(
      h6, 750, W17, 750, b17, nullptr, nullptr, nullptr, nullptr,
      nullptr, nullptr, h7, nullptr, 256, 750, 750);
  gemm_k<EPI_PLAIN, false, false><<<NB(256, 750), TB, 0, stream>>>(
      h7, 750, W18, 750, b18, nullptr, nullptr, nullptr, nullptr,
      nullptr, nullptr, d_out, nullptr, 256, 750, 750);
  #undef NB
}

// Round 2
// 1111.972 us; speedup vs baseline: 9.2831x; 9.2831x over previous
//
#include <hip/hip_runtime.h>

#define EPS 1e-5f

typedef __attribute__((ext_vector_type(8))) short s8v;   // 8 x bf16 bits
typedef __attribute__((ext_vector_type(4))) float f4v;   // MFMA accumulator

__device__ __forceinline__ unsigned short f2b(float x) {
  unsigned int u = __float_as_uint(x);
  u += 0x7FFFu + ((u >> 16) & 1u);
  return (unsigned short)(u >> 16);
}
__device__ __forceinline__ float b2f(unsigned short b) {
  return __uint_as_float(((unsigned int)b) << 16);
}

// ---------------------------------------------------------------------------
// Split-K GEMM: C_partial[ky] = A(256 x K, bf16, lda padded to 32, zero-padded)
//             @ B(N x K, f32 row-major)^T   over K-chunk ky.
// Tile: 256 x 32, BK=32, 4 waves (wave w owns rows w*64..w*64+63).
// Grid: NT*KS blocks, ky = bid % KS (consecutive ids share nt -> chunk/XCD affinity).
// ---------------------------------------------------------------------------
__global__ __launch_bounds__(256)
void gemm_splitk(const unsigned short* __restrict__ A, int lda,
                 const float* __restrict__ B, int ldb,
                 float* __restrict__ P, int N, int K, int kchunk, int KS)
{
  __shared__ unsigned short As[256 * 40];
  __shared__ unsigned short Bs[32 * 40];
  const int bid = (int)blockIdx.x;
  const int ky = bid % KS, nt = bid / KS;
  const int n0 = nt << 5;
  const int t = threadIdx.x, lane = t & 63, w = t >> 6;
  const int lr = lane & 15, lk = lane >> 4;

  const int kstart = ky * kchunk;
  const int kend = min(K, kstart + kchunk);
  const int nfull = (kend - kstart) >> 5;
  const int rem = (kend - kstart) & 31;

  const int ar0 = t >> 2, akc = t & 3;   // A slots: rows ar0 + j*64, 8-bf16 chunk akc
  const int br0 = t >> 4, bkh = t & 15;  // B slots: rows br0 + j*16, float2 col bkh

  f4v acc[4][2] = {};

  s8v a_cur[4]; float2 b_cur[2];
  s8v a_nxt[4]; float2 b_nxt[2];

  auto loadA = [&](s8v* dst, int kb) {
    #pragma unroll
    for (int j = 0; j < 4; ++j)
      dst[j] = *(const s8v*)(A + (size_t)(ar0 + j * 64) * lda + kb + akc * 8);
  };
  auto loadB = [&](float2* dst, int kb) {
    #pragma unroll
    for (int j = 0; j < 2; ++j) {
      const int row = n0 + br0 + j * 16;
      if (row < N) dst[j] = *(const float2*)(B + (size_t)row * ldb + kb + bkh * 2);
      else { dst[j].x = 0.f; dst[j].y = 0.f; }
    }
  };
  auto stage = [&](const s8v* av, const float2* bv) {
    #pragma unroll
    for (int j = 0; j < 4; ++j)
      *(s8v*)(As + (ar0 + j * 64) * 40 + akc * 8) = av[j];
    #pragma unroll
    for (int j = 0; j < 2; ++j) {
      unsigned int pk = (unsigned int)f2b(bv[j].x) | ((unsigned int)f2b(bv[j].y) << 16);
      *(unsigned int*)(Bs + (br0 + j * 16) * 40 + bkh * 2) = pk;
    }
  };
  auto domfma = [&]() {
    s8v af[4], bf[2];
    #pragma unroll
    for (int fm = 0; fm < 4; ++fm)
      af[fm] = *(const s8v*)(As + (w * 64 + fm * 16 + lr) * 40 + lk * 8);
    #pragma unroll
    for (int fn = 0; fn < 2; ++fn)
      bf[fn] = *(const s8v*)(Bs + (fn * 16 + lr) * 40 + lk * 8);
    #pragma unroll
    for (int fm = 0; fm < 4; ++fm)
      #pragma unroll
      for (int fn = 0; fn < 2; ++fn)
        acc[fm][fn] = __builtin_amdgcn_mfma_f32_16x16x32_bf16(af[fm], bf[fn], acc[fm][fn], 0, 0, 0);
  };

  int kb = kstart;
  if (nfull > 0) {
    loadA(a_cur, kb); loadB(b_cur, kb);
    for (int s = 0; s < nfull; ++s) {
      stage(a_cur, b_cur);
      __syncthreads();
      const bool more = (s + 1 < nfull);
      if (more) { loadA(a_nxt, kb + 32); loadB(b_nxt, kb + 32); }
      domfma();
      __syncthreads();
      if (more) {
        #pragma unroll
        for (int j = 0; j < 4; ++j) a_cur[j] = a_nxt[j];
        b_cur[0] = b_nxt[0]; b_cur[1] = b_nxt[1];
        kb += 32;
      }
    }
    kb += 32;
  }
  if (rem) {
    loadA(a_cur, kb);  // pads are zero by construction
    #pragma unroll
    for (int j = 0; j < 2; ++j) {
      const int row = n0 + br0 + j * 16;
      const int kk = kb + bkh * 2;
      float e0 = (row < N && kk < K) ? B[(size_t)row * ldb + kk] : 0.f;
      float e1 = (row < N && kk + 1 < K) ? B[(size_t)row * ldb + kk + 1] : 0.f;
      b_cur[j].x = e0; b_cur[j].y = e1;
    }
    stage(a_cur, b_cur);
    __syncthreads();
    domfma();
    __syncthreads();
  }

  float* Pk = P + (size_t)ky * 256 * N;
  #pragma unroll
  for (int fm = 0; fm < 4; ++fm)
    #pragma unroll
    for (int fn = 0; fn < 2; ++fn) {
      const int col = n0 + fn * 16 + lr;
      if (col >= N) continue;
      #pragma unroll
      for (int j = 0; j < 4; ++j) {
        const int row = w * 64 + fm * 16 + lk * 4 + j;
        Pk[(size_t)row * N + col] = acc[fm][fn][j];
      }
    }
}

// Reduce over KS partials + epilogue. Writes bf16 activation (zero pads) or f32 out.
template<bool BN, bool RES, bool WRD, bool F32OUT>
__global__ __launch_bounds__(256)
void reduce_k(const float* __restrict__ P, int KS, int N, int ldc,
              const float* __restrict__ bias,
              const float* __restrict__ g, const float* __restrict__ bb,
              const float* __restrict__ rm, const float* __restrict__ rv,
              float* __restrict__ dR, unsigned short* __restrict__ Cb,
              float* __restrict__ Cf)
{
  const int idx = (int)blockIdx.x * 256 + threadIdx.x;
  if (idx >= 256 * ldc) return;
  const int row = idx / ldc, c = idx % ldc;
  if (c >= N) { if (!F32OUT) Cb[idx] = 0; return; }
  float v = 0.f;
  const float* p = P + (size_t)row * N + c;
  for (int k = 0; k < KS; ++k) v += p[(size_t)k * 256 * N];
  v += bias[c];
  if (BN) { const float s = g[c] * rsqrtf(rv[c] + EPS); v = (v - rm[c]) * s + bb[c]; }
  v = fmaxf(v, 0.f);
  if (RES) v += dR[(size_t)row * N + c];
  if (WRD) dR[(size_t)row * N + c] = v;
  if (F32OUT) Cf[(size_t)row * N + c] = v;
  else Cb[idx] = f2b(v);
}

__global__ __launch_bounds__(256)
void pack_x(const float* __restrict__ x, unsigned short* __restrict__ xg)
{
  const int idx = (int)blockIdx.x * 256 + threadIdx.x;
  if (idx < 256 * 16384) {
    const int r = idx >> 14, c = idx & 16383;
    xg[idx] = f2b(x[(size_t)r * 16437 + c]);
  }
}

__global__ void zpad_h5(unsigned short* __restrict__ h5)
{
  for (int idx = threadIdx.x; idx < 256 * 14; idx += 256) {
    const int b = idx / 14, j = idx % 14;
    h5[(size_t)b * 13344 + 13330 + j] = 0;
  }
}

// ---------------------------------------------------------------------------
// D3 / BN3 GEMM (round-1 kernel, kept: 9000-10664 blocks, latency already hidden)
// ---------------------------------------------------------------------------
enum { EPI_D3 = 2, EPI_BN3 = 3 };

template<int EPI, bool ABF16>
__global__ __launch_bounds__(256)
void gemm_k(const void* Aptr, int lda,
            const float* __restrict__ Bw, int ldb,
            const float* __restrict__ bias,
            const float* __restrict__ q0, const float* __restrict__ q1,
            const float* __restrict__ q2, const float* __restrict__ q3,
            const void* aux0, const float* __restrict__ aux1,
            void* Cptr, int M, int N, int K)
{
  __shared__ unsigned short As[64 * 40];
  __shared__ unsigned short Bs[64 * 40];
  const int t  = threadIdx.x;
  const int MT = M >> 6;
  const int mt = (int)blockIdx.x % MT;
  const int nt = (int)blockIdx.x / MT;
  const int m0 = mt << 6, n0 = nt << 6;

  const int lane = t & 63, w = t >> 6;
  const int wm = (w >> 1) << 5, wn = (w & 1) << 5;
  const int lr = lane & 15, lk = lane >> 4;
  const int sr = t >> 5, sk = t & 31;

  f4v acc[2][2] = {};

  for (int k0 = 0; k0 < K; k0 += 32) {
    const int kg = k0 + sk;
    const bool kin = (kg < K);
    #pragma unroll
    for (int it = 0; it < 8; ++it) {
      const int row = sr + (it << 3);
      float av = 0.f;
      if (kin) {
        if (ABF16) av = b2f(((const unsigned short*)Aptr)[(size_t)(m0 + row) * lda + kg]);
        else       av = ((const float*)Aptr)[(size_t)(m0 + row) * lda + kg];
      }
      As[row * 40 + sk] = f2b(av);
      const int brow = n0 + row;
      float bv = 0.f;
      if (kin && brow < N) bv = Bw[(size_t)brow * ldb + kg];
      Bs[row * 40 + sk] = f2b(bv);
    }
    __syncthreads();
    s8v a0 = *(const s8v*)(As + (wm + lr) * 40 + lk * 8);
    s8v a1 = *(const s8v*)(As + (wm + 16 + lr) * 40 + lk * 8);
    s8v b0 = *(const s8v*)(Bs + (wn + lr) * 40 + lk * 8);
    s8v b1 = *(const s8v*)(Bs + (wn + 16 + lr) * 40 + lk * 8);
    acc[0][0] = __builtin_amdgcn_mfma_f32_16x16x32_bf16(a0, b0, acc[0][0], 0, 0, 0);
    acc[0][1] = __builtin_amdgcn_mfma_f32_16x16x32_bf16(a0, b1, acc[0][1], 0, 0, 0);
    acc[1][0] = __builtin_amdgcn_mfma_f32_16x16x32_bf16(a1, b0, acc[1][0], 0, 0, 0);
    acc[1][1] = __builtin_amdgcn_mfma_f32_16x16x32_bf16(a1, b1, acc[1][1], 0, 0, 0);
    __syncthreads();
  }

  #pragma unroll
  for (int fm = 0; fm < 2; ++fm)
    #pragma unroll
    for (int fn = 0; fn < 2; ++fn)
      #pragma unroll
      for (int j = 0; j < 4; ++j) {
        const int row = m0 + wm + fm * 16 + lk * 4 + j;
        const int col = n0 + wn + fn * 16 + lr;
        if (col >= N) continue;
        float v = acc[fm][fn][j];
        const size_t idx = (size_t)row * (size_t)N + col;
        if (EPI == EPI_D3) {
          const int i = col / 54;
          v += bias[col];
          v = fmaf(b2f(((const unsigned short*)aux0)[(size_t)row * 2688 + i]),
                   aux1[(size_t)col * 54 + 53], v);
          ((unsigned short*)Cptr)[idx] = f2b(v);
        } else { // EPI_BN3
          const int i = row % 2666;
          v += bias[col];
          const float s = q0[i] * rsqrtf(q3[i] + EPS);
          v = (v - q2[i]) * s + q1[i];
          v = fmaxf(v, 0.f);
          ((unsigned short*)Cptr)[idx] = f2b(v);
        }
      }
}

__global__ __launch_bounds__(256)
void w15_k(const unsigned short* __restrict__ H, const float* __restrict__ W15,
           const float* __restrict__ b15,
           const float* __restrict__ g, const float* __restrict__ bb,
           const float* __restrict__ rm, const float* __restrict__ rv,
           unsigned short* __restrict__ out)
{
  __shared__ float wsh[5 * 54 + 5];
  const int t = threadIdx.x;
  for (int idx = t; idx < 270; idx += 256) wsh[idx] = W15[idx];
  if (t < 5) wsh[270 + t] = b15[t];
  __syncthreads();
  const size_t rr = (size_t)blockIdx.x * 256 + t;
  float hv[54];
  #pragma unroll
  for (int c = 0; c < 54; ++c) hv[c] = b2f(H[rr * 54 + c]);
  const int i = (int)(rr % 2666);
  const int b = (int)(rr / 2666);
  const float s = g[i] * rsqrtf(rv[i] + EPS);
  #pragma unroll
  for (int p = 0; p < 5; ++p) {
    float a = wsh[270 + p];
    #pragma unroll
    for (int c = 0; c < 54; ++c) a = fmaf(hv[c], wsh[p * 54 + c], a);
    a = (a - rm[i]) * s + bb[i];
    out[(size_t)b * 13344 + i * 5 + p] = f2b(fmaxf(a, 0.f));
  }
}

extern "C" void kernel_launch(void* const* d_in, const int* in_sizes, int n_in,
                              void* d_out, int out_size, void* d_ws, size_t ws_size,
                              hipStream_t stream)
{
  const float* x    = (const float*)d_in[0];
  const float* W1   = (const float*)d_in[1];
  const float* b1   = (const float*)d_in[2];
  const float* Wmid = (const float*)d_in[3];
  const float* bmid = (const float*)d_in[4];
  const float* bng  = (const float*)d_in[5];
  const float* bnb  = (const float*)d_in[6];
  const float* bnrm = (const float*)d_in[7];
  const float* bnrv = (const float*)d_in[8];
  const float* Wlin = (const float*)d_in[9];
  const float* blin = (const float*)d_in[10];
  const float* W13  = (const float*)d_in[11];
  const float* b13  = (const float*)d_in[12];
  const float* W14  = (const float*)d_in[13];
  const float* b14  = (const float*)d_in[14];
  const float* W15  = (const float*)d_in[15];
  const float* b15  = (const float*)d_in[16];
  const float* bn3g = (const float*)d_in[17];
  const float* bn3b = (const float*)d_in[18];
  const float* bn3rm= (const float*)d_in[19];
  const float* bn3rv= (const float*)d_in[20];
  const float* W16  = (const float*)d_in[21];
  const float* b16  = (const float*)d_in[22];
  const float* W17  = (const float*)d_in[23];
  const float* b17  = (const float*)d_in[24];
  const float* W18  = (const float*)d_in[25];
  const float* b18  = (const float*)d_in[26];

  const int R = 2666;
  char* p = (char*)d_ws;
  unsigned short* xg  = (unsigned short*)p; p += (size_t)256 * 16384 * 2;
  unsigned short* hA  = (unsigned short*)p; p += (size_t)256 * 2688 * 2;
  unsigned short* hB  = (unsigned short*)p; p += (size_t)256 * 2688 * 2;
  float*          dR  = (float*)p;          p += (size_t)256 * 2666 * 4;
  unsigned short* h5b = (unsigned short*)p; p += (size_t)256 * 13344 * 2;
  unsigned short* h6b = (unsigned short*)p; p += (size_t)256 * 768 * 2;
  unsigned short* h7b = (unsigned short*)p; p += (size_t)256 * 768 * 2;
  // big region: split-K partials (<=43.7MB)早 then d3/h3 bf16 (73.7MB), then partials again
  float* P = (float*)p;
  unsigned short* big0 = (unsigned short*)p;

  dim3 TB(256);

  pack_x<<<dim3(16384), TB, 0, stream>>>(x, xg);

  // L1: 256x2666, K=16384. NT=84, KS=16, chunk=1024.
  gemm_splitk<<<dim3(84 * 16), TB, 0, stream>>>(xg, 16384, W1, 16384, P, R, 16384, 1024, 16);
  reduce_k<true, false, true, false><<<dim3(2688), TB, 0, stream>>>(
      P, 16, R, 2688, b1, bng, bnb, bnrm, bnrv, dR, hA, nullptr);

  // mids: K=2666, NT=84, KS=14, chunk=192
  unsigned short* cur = hA; unsigned short* nxt = hB;
  for (int k = 0; k < 11; ++k) {
    gemm_splitk<<<dim3(84 * 14), TB, 0, stream>>>(
        cur, 2688, Wmid + (size_t)k * R * R, R, P, R, R, 192, 14);
    const int L = k + 1;
    if (k == 10 || (k & 1) == 0)
      reduce_k<true, false, false, false><<<dim3(2688), TB, 0, stream>>>(
          P, 14, R, 2688, bmid + (size_t)k * R,
          bng + (size_t)L * R, bnb + (size_t)L * R, bnrm + (size_t)L * R, bnrv + (size_t)L * R,
          nullptr, nxt, nullptr);
    else
      reduce_k<true, true, true, false><<<dim3(2688), TB, 0, stream>>>(
          P, 14, R, 2688, bmid + (size_t)k * R,
          bng + (size_t)L * R, bnb + (size_t)L * R, bnrm + (size_t)L * R, bnrv + (size_t)L * R,
          dR, nxt, nullptr);
    unsigned short* tmp = cur; cur = nxt; nxt = tmp;
  }
  const unsigned short* hfin = cur;  // bf16, stride 2688

  // d3 GEMM: env(256x53) @ Wlin^T(143964x53), epilogue adds h*wlin[:,:,53]+blin -> big0
  gemm_k<EPI_D3, false><<<dim3(4 * 2250), TB, 0, stream>>>(
      x + 16384, 16437, Wlin, 54, blin, nullptr, nullptr, nullptr, nullptr,
      hfin, Wlin, big0, 256, 143964, 53);

  // W13 / W14: (682496 x 54) @ (54x54)^T, bn3, in-place bf16
  gemm_k<EPI_BN3, true><<<dim3(10664), TB, 0, stream>>>(
      big0, 54, W13, 54, b13, bn3g, bn3b, bn3rm, bn3rv,
      nullptr, nullptr, big0, 682496, 54, 54);
  gemm_k<EPI_BN3, true><<<dim3(10664), TB, 0, stream>>>(
      big0, 54, W14, 54, b14, bn3g + R, bn3b + R, bn3rm + R, bn3rv + R,
      nullptr, nullptr, big0, 682496, 54, 54);

  // W15 -> h5b (bf16, 256 x 13344 padded)
  w15_k<<<dim3(2666), TB, 0, stream>>>(big0, W15, b15,
      bn3g + 2 * R, bn3b + 2 * R, bn3rm + 2 * R, bn3rv + 2 * R, h5b);
  zpad_h5<<<dim3(1), TB, 0, stream>>>(h5b);

  // W16: 256x750, K=13330. NT=24, KS=30, chunk=448.  (P reuses big region; big0 dead)
  gemm_splitk<<<dim3(24 * 30), TB, 0, stream>>>(h5b, 13344, W16, 13330, P, 750, 13330, 448, 30);
  reduce_k<false, false, false, false><<<dim3(768), TB, 0, stream>>>(
      P, 30, 750, 768, b16, nullptr, nullptr, nullptr, nullptr, nullptr, h6b, nullptr);

  // W17: K=750, KS=12, chunk=64
  gemm_splitk<<<dim3(24 * 12), TB, 0, stream>>>(h6b, 768, W17, 750, P, 750, 750, 64, 12);
  reduce_k<false, false, false, false><<<dim3(768), TB, 0, stream>>>(
      P, 12, 750, 768, b17, nullptr, nullptr, nullptr, nullptr, nullptr, h7b, nullptr);

  // W18: final -> f32 d_out
  gemm_splitk<<<dim3(24 * 12), TB, 0, stream>>>(h7b, 768, W18, 750, P, 750, 750, 64, 12);
  reduce_k<false, false, false, true><<<dim3(750), TB, 0, stream>>>(
      P, 12, 750, 750, b18, nullptr, nullptr, nullptr, nullptr, nullptr, nullptr, (float*)d_out);
}

// Round 3
// 783.111 us; speedup vs baseline: 13.1815x; 1.4199x over previous
//
#include <hip/hip_runtime.h>

#define EPS 1e-5f

typedef __attribute__((ext_vector_type(8))) short s8v;   // 8 x bf16 bits
typedef __attribute__((ext_vector_type(4))) float f4v;   // MFMA accumulator

__device__ __forceinline__ unsigned short f2b(float x) {
  unsigned int u = __float_as_uint(x);
  u += 0x7FFFu + ((u >> 16) & 1u);
  return (unsigned short)(u >> 16);
}
__device__ __forceinline__ float b2f(unsigned short b) {
  return __uint_as_float(((unsigned int)b) << 16);
}

// ---------------------------------------------------------------------------
// Split-K GEMM (unchanged structure from round 2; KS tuned down by caller)
// ---------------------------------------------------------------------------
__global__ __launch_bounds__(256)
void gemm_splitk(const unsigned short* __restrict__ A, int lda,
                 const float* __restrict__ B, int ldb,
                 float* __restrict__ P, int N, int K, int kchunk, int KS)
{
  __shared__ unsigned short As[256 * 40];
  __shared__ unsigned short Bs[32 * 40];
  const int bid = (int)blockIdx.x;
  const int ky = bid % KS, nt = bid / KS;
  const int n0 = nt << 5;
  const int t = threadIdx.x, lane = t & 63, w = t >> 6;
  const int lr = lane & 15, lk = lane >> 4;

  const int kstart = ky * kchunk;
  const int kend = min(K, kstart + kchunk);
  const int nfull = (kend - kstart) >> 5;
  const int rem = (kend - kstart) & 31;

  const int ar0 = t >> 2, akc = t & 3;
  const int br0 = t >> 4, bkh = t & 15;

  f4v acc[4][2] = {};

  s8v a_cur[4]; float2 b_cur[2];
  s8v a_nxt[4]; float2 b_nxt[2];

  auto loadA = [&](s8v* dst, int kb) {
    #pragma unroll
    for (int j = 0; j < 4; ++j)
      dst[j] = *(const s8v*)(A + (size_t)(ar0 + j * 64) * lda + kb + akc * 8);
  };
  auto loadB = [&](float2* dst, int kb) {
    #pragma unroll
    for (int j = 0; j < 2; ++j) {
      const int row = n0 + br0 + j * 16;
      if (row < N) dst[j] = *(const float2*)(B + (size_t)row * ldb + kb + bkh * 2);
      else { dst[j].x = 0.f; dst[j].y = 0.f; }
    }
  };
  auto stage = [&](const s8v* av, const float2* bv) {
    #pragma unroll
    for (int j = 0; j < 4; ++j)
      *(s8v*)(As + (ar0 + j * 64) * 40 + akc * 8) = av[j];
    #pragma unroll
    for (int j = 0; j < 2; ++j) {
      unsigned int pk = (unsigned int)f2b(bv[j].x) | ((unsigned int)f2b(bv[j].y) << 16);
      *(unsigned int*)(Bs + (br0 + j * 16) * 40 + bkh * 2) = pk;
    }
  };
  auto domfma = [&]() {
    s8v af[4], bf[2];
    #pragma unroll
    for (int fm = 0; fm < 4; ++fm)
      af[fm] = *(const s8v*)(As + (w * 64 + fm * 16 + lr) * 40 + lk * 8);
    #pragma unroll
    for (int fn = 0; fn < 2; ++fn)
      bf[fn] = *(const s8v*)(Bs + (fn * 16 + lr) * 40 + lk * 8);
    #pragma unroll
    for (int fm = 0; fm < 4; ++fm)
      #pragma unroll
      for (int fn = 0; fn < 2; ++fn)
        acc[fm][fn] = __builtin_amdgcn_mfma_f32_16x16x32_bf16(af[fm], bf[fn], acc[fm][fn], 0, 0, 0);
  };

  int kb = kstart;
  if (nfull > 0) {
    loadA(a_cur, kb); loadB(b_cur, kb);
    for (int s = 0; s < nfull; ++s) {
      stage(a_cur, b_cur);
      __syncthreads();
      const bool more = (s + 1 < nfull);
      if (more) { loadA(a_nxt, kb + 32); loadB(b_nxt, kb + 32); }
      domfma();
      __syncthreads();
      if (more) {
        #pragma unroll
        for (int j = 0; j < 4; ++j) a_cur[j] = a_nxt[j];
        b_cur[0] = b_nxt[0]; b_cur[1] = b_nxt[1];
        kb += 32;
      }
    }
    kb += 32;
  }
  if (rem) {
    loadA(a_cur, kb);
    #pragma unroll
    for (int j = 0; j < 2; ++j) {
      const int row = n0 + br0 + j * 16;
      const int kk = kb + bkh * 2;
      float e0 = (row < N && kk < K) ? B[(size_t)row * ldb + kk] : 0.f;
      float e1 = (row < N && kk + 1 < K) ? B[(size_t)row * ldb + kk + 1] : 0.f;
      b_cur[j].x = e0; b_cur[j].y = e1;
    }
    stage(a_cur, b_cur);
    __syncthreads();
    domfma();
    __syncthreads();
  }

  float* Pk = P + (size_t)ky * 256 * N;
  #pragma unroll
  for (int fm = 0; fm < 4; ++fm)
    #pragma unroll
    for (int fn = 0; fn < 2; ++fn) {
      const int col = n0 + fn * 16 + lr;
      if (col >= N) continue;
      #pragma unroll
      for (int j = 0; j < 4; ++j) {
        const int row = w * 64 + fm * 16 + lk * 4 + j;
        Pk[(size_t)row * N + col] = acc[fm][fn][j];
      }
    }
}

// Reduce over KS partials + epilogue. WRT: write transposed bf16 (Ct[c*256+row]).
template<bool BN, bool RES, bool WRD, bool F32OUT, bool WRT>
__global__ __launch_bounds__(256)
void reduce_k(const float* __restrict__ P, int KS, int N, int ldc,
              const float* __restrict__ bias,
              const float* __restrict__ g, const float* __restrict__ bb,
              const float* __restrict__ rm, const float* __restrict__ rv,
              float* __restrict__ dR, unsigned short* __restrict__ Cb,
              float* __restrict__ Cf, unsigned short* __restrict__ Ct)
{
  const int idx = (int)blockIdx.x * 256 + threadIdx.x;
  if (idx >= 256 * ldc) return;
  const int row = idx / ldc, c = idx % ldc;
  if (c >= N) { if (!F32OUT && !WRT) Cb[idx] = 0; return; }
  float v = 0.f;
  const float* p = P + (size_t)row * N + c;
  for (int k = 0; k < KS; ++k) v += p[(size_t)k * 256 * N];
  v += bias[c];
  if (BN) { const float s = g[c] * rsqrtf(rv[c] + EPS); v = (v - rm[c]) * s + bb[c]; }
  v = fmaxf(v, 0.f);
  if (RES) v += dR[(size_t)row * N + c];
  if (WRD) dR[(size_t)row * N + c] = v;
  if (F32OUT) Cf[(size_t)row * N + c] = v;
  else if (WRT) Ct[(size_t)c * 256 + row] = f2b(v);
  else Cb[idx] = f2b(v);
}

__global__ __launch_bounds__(256)
void pack_x(const float* __restrict__ x, unsigned short* __restrict__ xg)
{
  const int idx = (int)blockIdx.x * 256 + threadIdx.x;
  if (idx < 256 * 16384) {
    const int r = idx >> 14, c = idx & 16383;
    xg[idx] = f2b(x[(size_t)r * 16437 + c]);
  }
}

// envb[256][72] bf16: cols 0..52 = env, 53..71 = 0 (col 53 filled per-block with h_i)
__global__ __launch_bounds__(256)
void env_pack(const float* __restrict__ x, unsigned short* __restrict__ envb)
{
  const int idx = (int)blockIdx.x * 256 + threadIdx.x;
  if (idx < 256 * 72) {
    const int b = idx / 72, c = idx % 72;
    envb[idx] = (c < 53) ? f2b(x[(size_t)b * 16437 + 16384 + c]) : (unsigned short)0;
  }
}

__global__ void zpad_h5(unsigned short* __restrict__ h5)
{
  for (int idx = threadIdx.x; idx < 256 * 14; idx += 256) {
    const int b = idx / 14, j = idx % 14;
    h5[(size_t)b * 13344 + 13330 + j] = 0;
  }
}

// ---------------------------------------------------------------------------
// Fused head: per unit i, chain of 4 GEMMs 256x64x64 entirely in LDS/regs.
//   S1: d3 = [env|h_i] @ Wlin[i]^T + blin[i]          (no BN, no relu)
//   S2: relu(bn3_0(d3 @ W13^T + b13))
//   S3: relu(bn3_1(..  @ W14^T + b14))
//   S4: relu(bn3_2(..  @ W15^T + b15)) -> h5b[:, i*5 .. i*5+5)
// Single act buffer (in-place): each wave owns rows w*64..w*64+63, reads its
// whole A-tile into regs before the epilogue overwrites it.
// ---------------------------------------------------------------------------
__global__ __launch_bounds__(256, 2)
void fused_head(const unsigned short* __restrict__ envb,
                const unsigned short* __restrict__ htr,
                const float* __restrict__ Wlin, const float* __restrict__ blin,
                const float* __restrict__ W13, const float* __restrict__ b13,
                const float* __restrict__ W14, const float* __restrict__ b14,
                const float* __restrict__ W15, const float* __restrict__ b15,
                const float* __restrict__ bn3g, const float* __restrict__ bn3b,
                const float* __restrict__ bn3rm, const float* __restrict__ bn3rv,
                unsigned short* __restrict__ h5b)
{
  __shared__ unsigned short act[256 * 72];   // 36.9 KB
  __shared__ unsigned short Wl[64 * 72];     // Wlin[i], later W14
  __shared__ unsigned short Wa[64 * 72];     // W13
  __shared__ unsigned short Wb[16 * 72];     // W15
  const int i = (int)blockIdx.x;
  const int t = threadIdx.x, lane = t & 63, w = t >> 6;
  const int lr = lane & 15, lk = lane >> 4;
  const int R = 2666;

  #pragma unroll
  for (int c8 = 0; c8 < 9; ++c8)
    *(s8v*)(act + t * 72 + c8 * 8) = *(const s8v*)(envb + t * 72 + c8 * 8);
  act[t * 72 + 53] = htr[(size_t)i * 256 + t];

  const float* wli = Wlin + (size_t)i * 2916;
  for (int idx = t; idx < 64 * 72; idx += 256) {
    const int r = idx / 72, f = idx % 72;
    Wl[idx] = (r < 54 && f < 54) ? f2b(wli[r * 54 + f]) : (unsigned short)0;
    Wa[idx] = (r < 54 && f < 54) ? f2b(W13[r * 54 + f]) : (unsigned short)0;
  }
  for (int idx = t; idx < 16 * 72; idx += 256) {
    const int r = idx / 72, f = idx % 72;
    Wb[idx] = (r < 5 && f < 54) ? f2b(W15[r * 54 + f]) : (unsigned short)0;
  }
  const float s0 = bn3g[i] * rsqrtf(bn3rv[i] + EPS), m0 = bn3rm[i], c0 = bn3b[i];
  const float s1 = bn3g[R+i] * rsqrtf(bn3rv[R+i] + EPS), m1 = bn3rm[R+i], c1 = bn3b[R+i];
  const float s2 = bn3g[2*R+i] * rsqrtf(bn3rv[2*R+i] + EPS), m2 = bn3rm[2*R+i], c2 = bn3b[2*R+i];
  __syncthreads();

  const int abase = (w * 64 + lr) * 72 + lk * 8;
  f4v acc[4][4];

  auto zacc = [&]() {
    #pragma unroll
    for (int a = 0; a < 4; ++a)
      #pragma unroll
      for (int b = 0; b < 4; ++b) acc[a][b] = f4v{0.f, 0.f, 0.f, 0.f};
  };
  auto gemm4 = [&](const unsigned short* B) {
    s8v af[2][4];
    #pragma unroll
    for (int ks = 0; ks < 2; ++ks)
      #pragma unroll
      for (int fm = 0; fm < 4; ++fm)
        af[ks][fm] = *(const s8v*)(act + abase + fm * 16 * 72 + ks * 32);
    #pragma unroll
    for (int fn = 0; fn < 4; ++fn) {
      s8v b0 = *(const s8v*)(B + (fn * 16 + lr) * 72 + lk * 8);
      s8v b1 = *(const s8v*)(B + (fn * 16 + lr) * 72 + 32 + lk * 8);
      #pragma unroll
      for (int fm = 0; fm < 4; ++fm) {
        acc[fm][fn] = __builtin_amdgcn_mfma_f32_16x16x32_bf16(af[0][fm], b0, acc[fm][fn], 0, 0, 0);
        acc[fm][fn] = __builtin_amdgcn_mfma_f32_16x16x32_bf16(af[1][fm], b1, acc[fm][fn], 0, 0, 0);
      }
    }
  };
  auto epi_bn = [&](const float* bias, float s, float m, float c) {
    #pragma unroll
    for (int fn = 0; fn < 4; ++fn) {
      const int o = fn * 16 + lr;
      const float bo = (o < 54) ? bias[o] : 0.f;
      #pragma unroll
      for (int fm = 0; fm < 4; ++fm)
        #pragma unroll
        for (int j = 0; j < 4; ++j) {
          const int row = w * 64 + fm * 16 + lk * 4 + j;
          float v = acc[fm][fn][j] + bo;
          v = (v - m) * s + c;
          v = fmaxf(v, 0.f);
          act[row * 72 + o] = (o < 54) ? f2b(v) : (unsigned short)0;
        }
    }
  };

  // S1: d3 (no BN, no relu)
  zacc(); gemm4(Wl);
  #pragma unroll
  for (int fn = 0; fn < 4; ++fn) {
    const int o = fn * 16 + lr;
    const float bl = (o < 54) ? blin[(size_t)i * 54 + o] : 0.f;
    #pragma unroll
    for (int fm = 0; fm < 4; ++fm)
      #pragma unroll
      for (int j = 0; j < 4; ++j) {
        const int row = w * 64 + fm * 16 + lk * 4 + j;
        float v = acc[fm][fn][j] + bl;
        act[row * 72 + o] = (o < 54) ? f2b(v) : (unsigned short)0;
      }
  }
  __syncthreads();                       // all waves done with Wl (Wlin[i])
  for (int idx = t; idx < 64 * 72; idx += 256) {
    const int r = idx / 72, f = idx % 72;
    Wl[idx] = (r < 54 && f < 54) ? f2b(W14[r * 54 + f]) : (unsigned short)0;
  }
  // S2 (W13)
  zacc(); gemm4(Wa); epi_bn(b13, s0, m0, c0);
  __syncthreads();                       // W14 visible in Wl
  // S3 (W14)
  zacc(); gemm4(Wl); epi_bn(b14, s1, m1, c1);
  // S4 (W15, N-tile 0 only)
  f4v a4[4] = {};
  {
    s8v af[2][4];
    #pragma unroll
    for (int ks = 0; ks < 2; ++ks)
      #pragma unroll
      for (int fm = 0; fm < 4; ++fm)
        af[ks][fm] = *(const s8v*)(act + abase + fm * 16 * 72 + ks * 32);
    s8v b0 = *(const s8v*)(Wb + lr * 72 + lk * 8);
    s8v b1 = *(const s8v*)(Wb + lr * 72 + 32 + lk * 8);
    #pragma unroll
    for (int fm = 0; fm < 4; ++fm) {
      a4[fm] = __builtin_amdgcn_mfma_f32_16x16x32_bf16(af[0][fm], b0, a4[fm], 0, 0, 0);
      a4[fm] = __builtin_amdgcn_mfma_f32_16x16x32_bf16(af[1][fm], b1, a4[fm], 0, 0, 0);
    }
  }
  if (lr < 5) {
    const float b5 = b15[lr];
    #pragma unroll
    for (int fm = 0; fm < 4; ++fm)
      #pragma unroll
      for (int j = 0; j < 4; ++j) {
        const int row = w * 64 + fm * 16 + lk * 4 + j;
        float v = a4[fm][j] + b5;
        v = (v - m2) * s2 + c2;
        v = fmaxf(v, 0.f);
        h5b[(size_t)row * 13344 + (size_t)i * 5 + lr] = f2b(v);
      }
  }
}

extern "C" void kernel_launch(void* const* d_in, const int* in_sizes, int n_in,
                              void* d_out, int out_size, void* d_ws, size_t ws_size,
                              hipStream_t stream)
{
  const float* x    = (const float*)d_in[0];
  const float* W1   = (const float*)d_in[1];
  const float* b1   = (const float*)d_in[2];
  const float* Wmid = (const float*)d_in[3];
  const float* bmid = (const float*)d_in[4];
  const float* bng  = (const float*)d_in[5];
  const float* bnb  = (const float*)d_in[6];
  const float* bnrm = (const float*)d_in[7];
  const float* bnrv = (const float*)d_in[8];
  const float* Wlin = (const float*)d_in[9];
  const float* blin = (const float*)d_in[10];
  const float* W13  = (const float*)d_in[11];
  const float* b13  = (const float*)d_in[12];
  const float* W14  = (const float*)d_in[13];
  const float* b14  = (const float*)d_in[14];
  const float* W15  = (const float*)d_in[15];
  const float* b15  = (const float*)d_in[16];
  const float* bn3g = (const float*)d_in[17];
  const float* bn3b = (const float*)d_in[18];
  const float* bn3rm= (const float*)d_in[19];
  const float* bn3rv= (const float*)d_in[20];
  const float* W16  = (const float*)d_in[21];
  const float* b16  = (const float*)d_in[22];
  const float* W17  = (const float*)d_in[23];
  const float* b17  = (const float*)d_in[24];
  const float* W18  = (const float*)d_in[25];
  const float* b18  = (const float*)d_in[26];

  const int R = 2666;
  char* p = (char*)d_ws;
  unsigned short* xg  = (unsigned short*)p; p += (size_t)256 * 16384 * 2;
  unsigned short* hA  = (unsigned short*)p; p += (size_t)256 * 2688 * 2;
  unsigned short* hB  = (unsigned short*)p; p += (size_t)256 * 2688 * 2;
  float*          dR  = (float*)p;          p += (size_t)256 * 2666 * 4;
  unsigned short* h5b = (unsigned short*)p; p += (size_t)256 * 13344 * 2;
  unsigned short* h6b = (unsigned short*)p; p += (size_t)256 * 768 * 2;
  unsigned short* h7b = (unsigned short*)p; p += (size_t)256 * 768 * 2;
  unsigned short* envb= (unsigned short*)p; p += (size_t)256 * 72 * 2;
  unsigned short* htr = (unsigned short*)p; p += (size_t)2666 * 256 * 2;
  float* P = (float*)p;   // split-K partials, <= 23.1 MB

  dim3 TB(256);

  pack_x<<<dim3(16384), TB, 0, stream>>>(x, xg);
  env_pack<<<dim3(72), TB, 0, stream>>>(x, envb);
  zpad_h5<<<dim3(1), TB, 0, stream>>>(h5b);

  // L1: K=16384, KS=8, chunk 2048
  gemm_splitk<<<dim3(84 * 8), TB, 0, stream>>>(xg, 16384, W1, 16384, P, R, 16384, 2048, 8);
  reduce_k<true, false, true, false, false><<<dim3(2688), TB, 0, stream>>>(
      P, 8, R, 2688, b1, bng, bnb, bnrm, bnrv, dR, hA, nullptr, nullptr);

  // mids: K=2666, KS=7, chunk 384
  unsigned short* cur = hA; unsigned short* nxt = hB;
  for (int k = 0; k < 11; ++k) {
    gemm_splitk<<<dim3(84 * 7), TB, 0, stream>>>(
        cur, 2688, Wmid + (size_t)k * R * R, R, P, R, R, 384, 7);
    const int L = k + 1;
    if (k == 10)
      reduce_k<true, false, false, false, true><<<dim3(2688), TB, 0, stream>>>(
          P, 7, R, 2688, bmid + (size_t)k * R,
          bng + (size_t)L * R, bnb + (size_t)L * R, bnrm + (size_t)L * R, bnrv + (size_t)L * R,
          nullptr, nullptr, nullptr, htr);
    else if ((k & 1) == 0)
      reduce_k<true, false, false, false, false><<<dim3(2688), TB, 0, stream>>>(
          P, 7, R, 2688, bmid + (size_t)k * R,
          bng + (size_t)L * R, bnb + (size_t)L * R, bnrm + (size_t)L * R, bnrv + (size_t)L * R,
          nullptr, nxt, nullptr, nullptr);
    else
      reduce_k<true, true, true, false, false><<<dim3(2688), TB, 0, stream>>>(
          P, 7, R, 2688, bmid + (size_t)k * R,
          bng + (size_t)L * R, bnb + (size_t)L * R, bnrm + (size_t)L * R, bnrv + (size_t)L * R,
          dR, nxt, nullptr, nullptr);
    unsigned short* tmp = cur; cur = nxt; nxt = tmp;
  }

  // Fused d3 -> W13 -> W14 -> W15 chain, one block per unit i
  fused_head<<<dim3(2666), TB, 0, stream>>>(
      envb, htr, Wlin, blin, W13, b13, W14, b14, W15, b15,
      bn3g, bn3b, bn3rm, bn3rv, h5b);

  // W16: K=13330, KS=30, chunk 448
  gemm_splitk<<<dim3(24 * 30), TB, 0, stream>>>(h5b, 13344, W16, 13330, P, 750, 13330, 448, 30);
  reduce_k<false, false, false, false, false><<<dim3(768), TB, 0, stream>>>(
      P, 30, 750, 768, b16, nullptr, nullptr, nullptr, nullptr, nullptr, h6b, nullptr, nullptr);

  // W17: K=750, KS=12, chunk 64
  gemm_splitk<<<dim3(24 * 12), TB, 0, stream>>>(h6b, 768, W17, 750, P, 750, 750, 64, 12);
  reduce_k<false, false, false, false, false><<<dim3(768), TB, 0, stream>>>(
      P, 12, 750, 768, b17, nullptr, nullptr, nullptr, nullptr, nullptr, h7b, nullptr, nullptr);

  // W18 -> f32 d_out
  gemm_splitk<<<dim3(24 * 12), TB, 0, stream>>>(h7b, 768, W18, 750, P, 750, 750, 64, 12);
  reduce_k<false, false, false, true, false><<<dim3(750), TB, 0, stream>>>(
      P, 12, 750, 750, b18, nullptr, nullptr, nullptr, nullptr, nullptr, nullptr, (float*)d_out, nullptr);
}